// Round 3
// baseline (164.132 us; speedup 1.0000x reference)
//
#include <hip/hip_runtime.h>

// CNN_pre_LSTM: per-sample pipeline
//   x(1,24) -> conv11(8,K3)+ReLU -> conv12(8,K3)+ReLU -> pool2
//          -> conv21(16,K3)+ReLU -> conv22(16,K3)+ReLU -> pool2 -> Linear(96->24)
// 131072 samples. Block = 512 threads = 8 waves, 64 samples/block, lane = sample.
// Channels split 8 ways across waves -> weight indices wave-uniform (SGPR operands).
// LDS per thread halved vs 4-wave version: 72KB/block, 2 blocks/CU = 16 waves/CU.
// LDS feature maps laid out [ch][pos][sample64]: stride-1 across lanes, conflict-free.

#define TPB 512

__launch_bounds__(TPB, 4)   // 4 waves/SIMD = 2 blocks/CU resident
__global__ void cnn_pre_lstm_kernel(
    const float* __restrict__ x,
    const float* __restrict__ w11, const float* __restrict__ b11,
    const float* __restrict__ w12, const float* __restrict__ b12,
    const float* __restrict__ w21, const float* __restrict__ b21,
    const float* __restrict__ w22, const float* __restrict__ b22,
    const float* __restrict__ Wl,  const float* __restrict__ bl,
    float* __restrict__ out)
{
    __shared__ float sA[12288];  // 48 KB: h1 [8][24][64] / h3 [16][12][64] / outbuf [64][25]
    __shared__ float sB[6144];   // 24 KB: xbuf [64][25] / h2p [8][12][64] / h4p [16][6][64]

    const int tid = threadIdx.x;
    const int ln  = tid & 63;
    const int wv  = __builtin_amdgcn_readfirstlane(tid >> 6);  // wave id 0..7

    // ---------------- Stage 0: coalesced load of 64 samples of x -------------
    {
        const float* xg = x + (size_t)blockIdx.x * (64 * 24);
        #pragma unroll
        for (int k = 0; k < 3; ++k) {
            int o = tid + k * TPB;           // 0..1535
            int s = o / 24, p = o % 24;
            sB[s * 25 + p] = xg[o];          // padded row 25
        }
    }
    __syncthreads();

    // ---------------- Stage 1: conv11 (1->8, K=3, pad1) + ReLU ---------------
    // wave w computes co = w; h1 -> sA [8][24][64]
    {
        const int co = wv;
        float w0 = w11[co*3+0], w1 = w11[co*3+1], w2 = w11[co*3+2];
        float bb = b11[co];

        float xm = 0.f, xc = sB[ln*25 + 0], xp;
        #pragma unroll
        for (int p = 0; p < 24; ++p) {
            xp = (p < 23) ? sB[ln*25 + p + 1] : 0.f;
            float a = fmaf(w0, xm, fmaf(w1, xc, fmaf(w2, xp, bb)));
            sA[co * 1536 + p * 64 + ln] = fmaxf(a, 0.f);
            xm = xc; xc = xp;
        }
    }
    __syncthreads();

    // ---------------- Stage 2: conv12 (8->8) + ReLU + pool2 ------------------
    // wave w: co = w; reads h1 (sA), writes h2p -> sB [8][12][64]
    {
        const int co = wv;
        float acc[24];
        {
            float bb = b12[co];
            #pragma unroll
            for (int p = 0; p < 24; ++p) acc[p] = bb;
        }
        for (int ci = 0; ci < 8; ++ci) {
            const float* wp = w12 + (co * 8 + ci) * 3;
            float w0 = wp[0], w1 = wp[1], w2 = wp[2];
            const int cb = ci * 1536 + ln;
            float xm = 0.f, xc = sA[cb], xp;
            #pragma unroll
            for (int p = 0; p < 24; ++p) {
                xp = (p < 23) ? sA[cb + (p + 1) * 64] : 0.f;
                acc[p] = fmaf(w0, xm, fmaf(w1, xc, fmaf(w2, xp, acc[p])));
                xm = xc; xc = xp;
            }
        }
        #pragma unroll
        for (int q = 0; q < 12; ++q)
            sB[co * 768 + q * 64 + ln] =
                fmaxf(fmaxf(acc[2*q], acc[2*q+1]), 0.f);
    }
    __syncthreads();

    // ---------------- Stage 3: conv21 (8->16) + ReLU -------------------------
    // wave w: co in {2w, 2w+1}; reads h2p (sB), writes h3 -> sA [16][12][64]
    {
        const int co0 = wv * 2;
        float acc[2][12];
        #pragma unroll
        for (int i = 0; i < 2; ++i) {
            float bb = b21[co0 + i];
            #pragma unroll
            for (int p = 0; p < 12; ++p) acc[i][p] = bb;
        }
        for (int ci = 0; ci < 8; ++ci) {
            float wg[2][3];
            #pragma unroll
            for (int i = 0; i < 2; ++i) {
                const float* wp = w21 + ((co0 + i) * 8 + ci) * 3;
                wg[i][0] = wp[0]; wg[i][1] = wp[1]; wg[i][2] = wp[2];
            }
            const int cb = ci * 768 + ln;
            float xm = 0.f, xc = sB[cb], xp;
            #pragma unroll
            for (int p = 0; p < 12; ++p) {
                xp = (p < 11) ? sB[cb + (p + 1) * 64] : 0.f;
                #pragma unroll
                for (int i = 0; i < 2; ++i)
                    acc[i][p] = fmaf(wg[i][0], xm, fmaf(wg[i][1], xc, fmaf(wg[i][2], xp, acc[i][p])));
                xm = xc; xc = xp;
            }
        }
        #pragma unroll
        for (int i = 0; i < 2; ++i)
            #pragma unroll
            for (int p = 0; p < 12; ++p)
                sA[(co0 + i) * 768 + p * 64 + ln] = fmaxf(acc[i][p], 0.f);
    }
    __syncthreads();

    // ---------------- Stage 4: conv22 (16->16) + ReLU + pool2 ----------------
    // wave w: co in {2w, 2w+1}; reads h3 (sA), writes h4p -> sB [16][6][64]
    {
        const int co0 = wv * 2;
        float acc[2][12];
        #pragma unroll
        for (int i = 0; i < 2; ++i) {
            float bb = b22[co0 + i];
            #pragma unroll
            for (int p = 0; p < 12; ++p) acc[i][p] = bb;
        }
        for (int ci = 0; ci < 16; ++ci) {
            float wg[2][3];
            #pragma unroll
            for (int i = 0; i < 2; ++i) {
                const float* wp = w22 + ((co0 + i) * 16 + ci) * 3;
                wg[i][0] = wp[0]; wg[i][1] = wp[1]; wg[i][2] = wp[2];
            }
            const int cb = ci * 768 + ln;
            float xm = 0.f, xc = sA[cb], xp;
            #pragma unroll
            for (int p = 0; p < 12; ++p) {
                xp = (p < 11) ? sA[cb + (p + 1) * 64] : 0.f;
                #pragma unroll
                for (int i = 0; i < 2; ++i)
                    acc[i][p] = fmaf(wg[i][0], xm, fmaf(wg[i][1], xc, fmaf(wg[i][2], xp, acc[i][p])));
                xm = xc; xc = xp;
            }
        }
        #pragma unroll
        for (int i = 0; i < 2; ++i)
            #pragma unroll
            for (int q = 0; q < 6; ++q)
                sB[(co0 + i) * 384 + q * 64 + ln] =
                    fmaxf(fmaxf(acc[i][2*q], acc[i][2*q+1]), 0.f);
    }
    __syncthreads();

    // ---------------- Stage 5: Linear (96 -> 24) -----------------------------
    // feature f = c*6 + p (torch reshape order). wave w: out j in {3w..3w+2}.
    {
        const int j0 = wv * 3;
        float acc3[3];
        #pragma unroll
        for (int i = 0; i < 3; ++i) acc3[i] = bl[j0 + i];
        for (int c = 0; c < 16; ++c) {
            #pragma unroll
            for (int p = 0; p < 6; ++p) {
                float v = sB[c * 384 + p * 64 + ln];
                const int f = c * 6 + p;
                #pragma unroll
                for (int i = 0; i < 3; ++i)
                    acc3[i] = fmaf(Wl[(j0 + i) * 96 + f], v, acc3[i]);
            }
        }
        // outbuf padded [64][25]: lane stride 25 (odd) -> conflict-free writes
        #pragma unroll
        for (int i = 0; i < 3; ++i)
            sA[ln * 25 + j0 + i] = acc3[i];
    }
    __syncthreads();

    // ---------------- Stage 6: coalesced store -------------------------------
    {
        float* og = out + (size_t)blockIdx.x * (64 * 24);
        #pragma unroll
        for (int k = 0; k < 3; ++k) {
            int o = tid + k * TPB;           // 0..1535
            int s = o / 24, j = o % 24;
            og[o] = sA[s * 25 + j];
        }
    }
}

extern "C" void kernel_launch(void* const* d_in, const int* in_sizes, int n_in,
                              void* d_out, int out_size, void* d_ws, size_t ws_size,
                              hipStream_t stream) {
    const float* x   = (const float*)d_in[0];
    const float* w11 = (const float*)d_in[1];
    const float* b11 = (const float*)d_in[2];
    const float* w12 = (const float*)d_in[3];
    const float* b12 = (const float*)d_in[4];
    const float* w21 = (const float*)d_in[5];
    const float* b21 = (const float*)d_in[6];
    const float* w22 = (const float*)d_in[7];
    const float* b22 = (const float*)d_in[8];
    const float* Wl  = (const float*)d_in[9];
    const float* bl  = (const float*)d_in[10];
    float* out = (float*)d_out;

    const int n_samples = in_sizes[0] / 24;    // 512*256 = 131072
    const int blocks = n_samples / 64;         // 2048

    hipLaunchKernelGGL(cnn_pre_lstm_kernel, dim3(blocks), dim3(TPB), 0, stream,
                       x, w11, b11, w12, b12, w21, b21, w22, b22, Wl, bl, out);
}